// Round 8
// baseline (523.250 us; speedup 1.0000x reference)
//
#include <hip/hip_runtime.h>
#include <cstdint>
#include <cstddef>

static constexpr float NEG_SLOPE_C = 0.2f;
static constexpr float EPS_C = 1e-16f;
static constexpr float LOG2E_C = 1.4426950408889634f;

#if defined(__has_builtin)
#if __has_builtin(__builtin_amdgcn_exp2f)
#define EXP2F(x) __builtin_amdgcn_exp2f(x)
#else
#define EXP2F(x) exp2f(x)
#endif
#else
#define EXP2F(x) exp2f(x)
#endif

typedef __attribute__((ext_vector_type(8))) short bf16x8;
typedef __attribute__((ext_vector_type(4))) float f32x4;

__device__ __forceinline__ short bf16_rne(float x) {
    unsigned u = __float_as_uint(x);
    u = (u + 0x7FFF + ((u >> 16) & 1)) >> 16;
    return (short)u;
}
__device__ __forceinline__ float bf16f(short s) {
    return __uint_as_float(((unsigned)(unsigned short)s) << 16);
}

// DPP-based partial-sum add: v += dpp_perm(v).
template<int CTRL>
__device__ __forceinline__ float dpp_add_f(float v) {
    int x = __builtin_amdgcn_update_dpp(0, __float_as_int(v), CTRL, 0xf, 0xf, true);
    return v + __int_as_float(x);
}

// 32-lane-half reduction of q (both heads at once), result in every lane.
__device__ __forceinline__ float half_reduce(float q) {
    q = dpp_add_f<0xB1>(q);      // xor1 (quad_perm [1,0,3,2])
    q = dpp_add_f<0x4E>(q);      // xor2 (quad_perm [2,3,0,1])
    q = dpp_add_f<0x141>(q);     // half-mirror: pairs quads
    q = dpp_add_f<0x140>(q);     // mirror: pairs octs
    q += __int_as_float(__builtin_amdgcn_ds_swizzle(__float_as_int(q), 0x401F)); // xor16
    return q;
}

// ---------------- CSR construction ----------------

__global__ void degree_kernel(const int* __restrict__ ei, const float* __restrict__ ew,
                              int E, int* __restrict__ cnt, float* __restrict__ wsum) {
    int e = blockIdx.x * blockDim.x + threadIdx.x;
    if (e >= E) return;
    int dst = ei[E + e];
    atomicAdd(&cnt[dst], 1);
    atomicAdd(&wsum[dst], ew[e]);
}

__global__ void scan_kernel(const int* __restrict__ cnt, const float* __restrict__ wsum,
                            int N, int E, int* __restrict__ offs, float* __restrict__ self_w) {
    __shared__ int bufA[1024];
    __shared__ int bufB[1024];
    int t = threadIdx.x;
    int chunk = (N + 1023) / 1024;
    int lo = t * chunk;
    int hi = lo + chunk; if (hi > N) hi = N; if (lo > N) lo = N;
    int s = 0;
    for (int n = lo; n < hi; ++n) s += cnt[n];
    bufA[t] = s;
    __syncthreads();
    int* srcb = bufA; int* dstb = bufB;
    for (int d = 1; d < 1024; d <<= 1) {
        int v = srcb[t];
        if (t >= d) v += srcb[t - d];
        dstb[t] = v;
        __syncthreads();
        int* tmp = srcb; srcb = dstb; dstb = tmp;
    }
    int run = (t == 0) ? 0 : srcb[t - 1];
    for (int n = lo; n < hi; ++n) { offs[n] = run; run += cnt[n]; }
    if (t == 0) offs[N] = E;
    for (int n = t; n < N; n += 1024) {
        int c = cnt[n];
        self_w[n] = (c > 0) ? (wsum[n] / (float)c) : 0.0f;
    }
}

__global__ void scatter_kernel(const int* __restrict__ ei, const float* __restrict__ ew, int E,
                               const int* __restrict__ offs, int* __restrict__ cursor,
                               int2* __restrict__ pairs) {
    int e = blockIdx.x * blockDim.x + threadIdx.x;
    if (e >= E) return;
    int dst = ei[E + e];
    int pos = offs[dst] + atomicAdd(&cursor[dst], 1);
    pairs[pos] = make_int2(ei[e], __float_as_int(ew[e]));
}

// ---------------- W prep: transpose + split fp32 -> bf16 hi/lo planes ----------
// Wt[n][k], n in [0,256): n<128 = Wl col n, n>=128 = Wr col n-128. Fragment-
// order so gemm B-frag = 8 contiguous bf16 per lane (global_load_dwordx4).

template<int K>
__global__ void wprep_kernel(const float* __restrict__ Wl, const float* __restrict__ Wr,
                             short* __restrict__ Wth, short* __restrict__ Wtl) {
    const int k = blockIdx.x;
    const int t = threadIdx.x;
    const float v = (t < 128) ? Wl[k * 128 + t] : Wr[k * 128 + (t - 128)];
    const short h = bf16_rne(v);
    Wth[(size_t)t * K + k] = h;
    Wtl[(size_t)t * K + k] = bf16_rne(v - bf16f(h));
}

// ---------------- split-bf16 MFMA GEMM: [outL|outR] = X[R x K] @ [Wl|Wr] --------
// 64 rows x 256 cols per block (256 thr = 4 waves); wave w = row-tile w (16 rows)
// x 16 col-tiles of 16. 3 MFMA per tile-step (hi*hi + lo*hi + hi*lo) gives
// ~fp32 accuracy (lo*lo ~ 2^-18 dropped). No LDS, no barriers: A read once from
// global fp32 + split in-register; B frags from L2-resident pre-transposed Wt.
// Layouts (HW-verified m89/m91/m120): A[m=lane&15][k=(lane>>4)*8+j],
// B[n=lane&15][k same], D col=lane&15 row=(lane>>4)*4+reg.

template<int K>
__global__ __launch_bounds__(256) void gemm_mfma_kernel(
    const float* __restrict__ X,
    const short* __restrict__ Wth, const short* __restrict__ Wtl,
    float* __restrict__ outL, float* __restrict__ outR) {
    const int tid = threadIdx.x;
    const int wv = tid >> 6;
    const int lane = tid & 63;
    const int q = lane >> 4;
    const int mr = lane & 15;
    const int arow = blockIdx.x * 64 + wv * 16 + mr;

    f32x4 acc[16];
    #pragma unroll
    for (int t = 0; t < 16; ++t) acc[t] = (f32x4){0.f, 0.f, 0.f, 0.f};

    const float* ap = X + (size_t)arow * K + q * 8;
    const short* bh0 = Wth + (size_t)mr * K + q * 8;
    const short* bl0 = Wtl + (size_t)mr * K + q * 8;

    for (int k0 = 0; k0 < K; k0 += 32) {
        float4 a0 = *(const float4*)(ap + k0);
        float4 a1 = *(const float4*)(ap + k0 + 4);
        const float av[8] = {a0.x, a0.y, a0.z, a0.w, a1.x, a1.y, a1.z, a1.w};
        bf16x8 ah, al;
        #pragma unroll
        for (int j = 0; j < 8; ++j) {
            const short h = bf16_rne(av[j]);
            ah[j] = h;
            al[j] = bf16_rne(av[j] - bf16f(h));
        }
        #pragma unroll 4
        for (int t = 0; t < 16; ++t) {
            const bf16x8 bhv = *(const bf16x8*)(bh0 + (size_t)t * 16 * K + k0);
            const bf16x8 blv = *(const bf16x8*)(bl0 + (size_t)t * 16 * K + k0);
            acc[t] = __builtin_amdgcn_mfma_f32_16x16x32_bf16(ah, bhv, acc[t], 0, 0, 0);
            acc[t] = __builtin_amdgcn_mfma_f32_16x16x32_bf16(al, bhv, acc[t], 0, 0, 0);
            acc[t] = __builtin_amdgcn_mfma_f32_16x16x32_bf16(ah, blv, acc[t], 0, 0, 0);
        }
    }

    const int orow = blockIdx.x * 64 + wv * 16 + q * 4;
    #pragma unroll
    for (int t = 0; t < 8; ++t) {
        #pragma unroll
        for (int r = 0; r < 4; ++r) {
            outL[(size_t)(orow + r) * 128 + t * 16 + mr] = acc[t][r];
            outR[(size_t)(orow + r) * 128 + t * 16 + mr] = acc[t + 8][r];
        }
    }
}

// ---------------- fused edge softmax-aggregate (R7-proven, unchanged) ----------

__global__ __launch_bounds__(256) void edge_kernel(
    const float* __restrict__ xl, const float* __restrict__ xr,
    const int* __restrict__ offs, const int2* __restrict__ pairs,
    const float* __restrict__ self_w,
    const float* __restrict__ att, const float* __restrict__ We,
    const float* __restrict__ bias, float* __restrict__ out,
    int N, int M) {
    const int wave = __builtin_amdgcn_readfirstlane(threadIdx.x >> 6);
    const int b = blockIdx.x;
    const int hb = (b >= 10000) ? (b - 10000) : b;
    const int m = ((b >= 10000) ? 8 : 0) + (hb & 7);
    const int n = (hb >> 3) * 4 + wave;
    if (n >= N) return;
    const int lane = threadIdx.x & 63;

    const int c2 = lane << 1;
    float2 att2 = *(const float2*)(att + c2);
    att2.x *= LOG2E_C; att2.y *= LOG2E_C;     // exp2 domain
    const float2 we2 = *(const float2*)(We + c2);

    const float* xlm = xl + (size_t)m * N * 128;
    const float* xrm = xr + (size_t)m * N * 128;
    const int rowb = n << 7;
    const float2 xi2 = *(const float2*)(xrm + rowb + c2);

    float base, lsum;
    float2 acc;
    {   // self-loop first; its logit becomes the softmax base (t = 1)
        const float sw = self_w[n];
        const float2 xj = *(const float2*)(xlm + rowb + c2);
        float sx = fmaf(sw, we2.x, xi2.x) + xj.x;
        float sy = fmaf(sw, we2.y, xi2.y) + xj.y;
        sx = fmaf(NEG_SLOPE_C - 1.0f, fminf(sx, 0.f), sx);
        sy = fmaf(NEG_SLOPE_C - 1.0f, fminf(sy, 0.f), sy);
        base = half_reduce(fmaf(sy, att2.y, sx * att2.x));
        lsum = 1.f; acc = xj;
    }

    const int beg = offs[n], end = offs[n + 1];
    int e = beg;
    for (; e + 2 <= end; e += 2) {
        const int2 prA = pairs[e];
        const int2 prB = pairs[e + 1];
        const float wA = __int_as_float(prA.y);
        const float wB = __int_as_float(prB.y);
        const float2 xjA = *(const float2*)(xlm + (prA.x << 7) + c2);
        const float2 xjB = *(const float2*)(xlm + (prB.x << 7) + c2);
        float sxA = fmaf(wA, we2.x, xi2.x) + xjA.x;
        float syA = fmaf(wA, we2.y, xi2.y) + xjA.y;
        float sxB = fmaf(wB, we2.x, xi2.x) + xjB.x;
        float syB = fmaf(wB, we2.y, xi2.y) + xjB.y;
        sxA = fmaf(NEG_SLOPE_C - 1.0f, fminf(sxA, 0.f), sxA);
        syA = fmaf(NEG_SLOPE_C - 1.0f, fminf(syA, 0.f), syA);
        sxB = fmaf(NEG_SLOPE_C - 1.0f, fminf(sxB, 0.f), sxB);
        syB = fmaf(NEG_SLOPE_C - 1.0f, fminf(syB, 0.f), syB);
        float qA = half_reduce(fmaf(syA, att2.y, sxA * att2.x));
        float qB = half_reduce(fmaf(syB, att2.y, sxB * att2.x));
        const float tA = EXP2F(qA - base);
        const float tB = EXP2F(qB - base);
        lsum += tA + tB;
        acc.x = fmaf(tA, xjA.x, acc.x);
        acc.y = fmaf(tA, xjA.y, acc.y);
        acc.x = fmaf(tB, xjB.x, acc.x);
        acc.y = fmaf(tB, xjB.y, acc.y);
    }
    if (e < end) {
        const int2 pr = pairs[e];
        const float w = __int_as_float(pr.y);
        const float2 xj = *(const float2*)(xlm + (pr.x << 7) + c2);
        float sx = fmaf(w, we2.x, xi2.x) + xj.x;
        float sy = fmaf(w, we2.y, xi2.y) + xj.y;
        sx = fmaf(NEG_SLOPE_C - 1.0f, fminf(sx, 0.f), sx);
        sy = fmaf(NEG_SLOPE_C - 1.0f, fminf(sy, 0.f), sy);
        float q = half_reduce(fmaf(sy, att2.y, sx * att2.x));
        const float t = EXP2F(q - base);
        lsum += t;
        acc.x = fmaf(t, xj.x, acc.x);
        acc.y = fmaf(t, xj.y, acc.y);
    }

    const float inv = 1.f / (lsum + EPS_C);
    const float2 b2v = *(const float2*)(bias + c2);
    float ox = fmaf(acc.x, inv, b2v.x);
    float oy = fmaf(acc.y, inv, b2v.y);
    ox = ox > 0.f ? ox : (__expf(ox) - 1.f);   // ELU
    oy = oy > 0.f ? oy : (__expf(oy) - 1.f);
    *(float2*)(out + (size_t)m * N * 128 + rowb + c2) = make_float2(ox, oy);
}

// ---------------- launch ----------------

extern "C" void kernel_launch(void* const* d_in, const int* in_sizes, int n_in,
                              void* d_out, int out_size, void* d_ws, size_t ws_size,
                              hipStream_t stream) {
    const float* x    = (const float*)d_in[0];
    const int*   ei   = (const int*)d_in[1];
    const float* ew   = (const float*)d_in[2];
    const float* Wl1  = (const float*)d_in[3];
    const float* Wr1  = (const float*)d_in[4];
    const float* att1 = (const float*)d_in[5];
    const float* We1  = (const float*)d_in[6];
    const float* b1   = (const float*)d_in[7];
    const float* Wl2  = (const float*)d_in[8];
    const float* Wr2  = (const float*)d_in[9];
    const float* att2 = (const float*)d_in[10];
    const float* We2  = (const float*)d_in[11];
    const float* b2   = (const float*)d_in[12];

    const int E = in_sizes[1] / 2;
    const int N = 5000;                 // fixed by setup_inputs
    const int R = out_size / 128;       // M*N rows
    const int M = R / N;                // B*T = 16

    char* ws = (char*)d_ws;
    size_t off = 0;
    auto alloc = [&](size_t bytes) {
        char* p = ws + off;
        off = (off + bytes + 255) & ~(size_t)255;
        return p;
    };
    int*   cnt    = (int*)  alloc((size_t)N * 4);
    float* wsum   = (float*)alloc((size_t)N * 4);
    float* selfw  = (float*)alloc((size_t)N * 4);
    int*   offs   = (int*)  alloc((size_t)(N + 1) * 4);
    int*   cursor = (int*)  alloc((size_t)N * 4);
    int2*  pairs  = (int2*) alloc((size_t)E * 8);
    short* wt1h   = (short*)alloc((size_t)256 * 64 * 2);
    short* wt1l   = (short*)alloc((size_t)256 * 64 * 2);
    short* wt2h   = (short*)alloc((size_t)256 * 128 * 2);
    short* wt2l   = (short*)alloc((size_t)256 * 128 * 2);
    float* bufA   = (float*)alloc((size_t)R * 128 * 4);
    float* bufB   = (float*)alloc((size_t)R * 128 * 4);
    float* bufC   = (float*)alloc((size_t)R * 128 * 4);

    hipMemsetAsync(cnt,    0, (size_t)N * 4, stream);
    hipMemsetAsync(wsum,   0, (size_t)N * 4, stream);
    hipMemsetAsync(cursor, 0, (size_t)N * 4, stream);

    int eb = (E + 255) / 256;
    degree_kernel<<<eb, 256, 0, stream>>>(ei, ew, E, cnt, wsum);
    scan_kernel<<<1, 1024, 0, stream>>>(cnt, wsum, N, E, offs, selfw);
    scatter_kernel<<<eb, 256, 0, stream>>>(ei, ew, E, offs, cursor, pairs);
    wprep_kernel<64><<<64, 256, 0, stream>>>(Wl1, Wr1, wt1h, wt1l);
    wprep_kernel<128><<<128, 256, 0, stream>>>(Wl2, Wr2, wt2h, wt2l);

    const int gb = R / 64;
    const int tb = 2 * ((N + 3) / 4) * 8;   // 20000 blocks: XCD-swizzled task map

    // layer 1: K=64
    gemm_mfma_kernel<64><<<gb, 256, 0, stream>>>(x, wt1h, wt1l, bufA, bufB);
    edge_kernel<<<tb, 256, 0, stream>>>(bufA, bufB, offs, pairs, selfw,
                                        att1, We1, b1, bufC, N, M);
    // layer 2: K=128
    gemm_mfma_kernel<128><<<gb, 256, 0, stream>>>(bufC, wt2h, wt2l, bufA, bufB);
    edge_kernel<<<tb, 256, 0, stream>>>(bufA, bufB, offs, pairs, selfw,
                                        att2, We2, b2, (float*)d_out, N, M);
}

// Round 9
// 402.693 us; speedup vs baseline: 1.2994x; 1.2994x over previous
//
#include <hip/hip_runtime.h>
#include <cstdint>
#include <cstddef>

static constexpr float NEG_SLOPE_C = 0.2f;
static constexpr float EPS_C = 1e-16f;
static constexpr float LOG2E_C = 1.4426950408889634f;

#if defined(__has_builtin)
#if __has_builtin(__builtin_amdgcn_exp2f)
#define EXP2F(x) __builtin_amdgcn_exp2f(x)
#else
#define EXP2F(x) exp2f(x)
#endif
#else
#define EXP2F(x) exp2f(x)
#endif

typedef __attribute__((ext_vector_type(8))) short bf16x8;
typedef __attribute__((ext_vector_type(4))) float f32x4;

__device__ __forceinline__ short bf16_rne(float x) {
    unsigned u = __float_as_uint(x);
    u = (u + 0x7FFF + ((u >> 16) & 1)) >> 16;
    return (short)u;
}
__device__ __forceinline__ float bf16f(short s) {
    return __uint_as_float(((unsigned)(unsigned short)s) << 16);
}

// DPP-based partial-sum add: v += dpp_perm(v).
template<int CTRL>
__device__ __forceinline__ float dpp_add_f(float v) {
    int x = __builtin_amdgcn_update_dpp(0, __float_as_int(v), CTRL, 0xf, 0xf, true);
    return v + __int_as_float(x);
}

// 32-lane-half reduction of q (both heads at once), result in every lane.
__device__ __forceinline__ float half_reduce(float q) {
    q = dpp_add_f<0xB1>(q);      // xor1 (quad_perm [1,0,3,2])
    q = dpp_add_f<0x4E>(q);      // xor2 (quad_perm [2,3,0,1])
    q = dpp_add_f<0x141>(q);     // half-mirror: pairs quads
    q = dpp_add_f<0x140>(q);     // mirror: pairs octs
    q += __int_as_float(__builtin_amdgcn_ds_swizzle(__float_as_int(q), 0x401F)); // xor16
    return q;
}

// ---------------- CSR construction ----------------

__global__ void degree_kernel(const int* __restrict__ ei, const float* __restrict__ ew,
                              int E, int* __restrict__ cnt, float* __restrict__ wsum) {
    int e = blockIdx.x * blockDim.x + threadIdx.x;
    if (e >= E) return;
    int dst = ei[E + e];
    atomicAdd(&cnt[dst], 1);
    atomicAdd(&wsum[dst], ew[e]);
}

__global__ void scan_kernel(const int* __restrict__ cnt, const float* __restrict__ wsum,
                            int N, int E, int* __restrict__ offs, float* __restrict__ self_w) {
    __shared__ int bufA[1024];
    __shared__ int bufB[1024];
    int t = threadIdx.x;
    int chunk = (N + 1023) / 1024;
    int lo = t * chunk;
    int hi = lo + chunk; if (hi > N) hi = N; if (lo > N) lo = N;
    int s = 0;
    for (int n = lo; n < hi; ++n) s += cnt[n];
    bufA[t] = s;
    __syncthreads();
    int* srcb = bufA; int* dstb = bufB;
    for (int d = 1; d < 1024; d <<= 1) {
        int v = srcb[t];
        if (t >= d) v += srcb[t - d];
        dstb[t] = v;
        __syncthreads();
        int* tmp = srcb; srcb = dstb; dstb = tmp;
    }
    int run = (t == 0) ? 0 : srcb[t - 1];
    for (int n = lo; n < hi; ++n) { offs[n] = run; run += cnt[n]; }
    if (t == 0) offs[N] = E;
    for (int n = t; n < N; n += 1024) {
        int c = cnt[n];
        self_w[n] = (c > 0) ? (wsum[n] / (float)c) : 0.0f;
    }
}

__global__ void scatter_kernel(const int* __restrict__ ei, const float* __restrict__ ew, int E,
                               const int* __restrict__ offs, int* __restrict__ cursor,
                               int2* __restrict__ pairs) {
    int e = blockIdx.x * blockDim.x + threadIdx.x;
    if (e >= E) return;
    int dst = ei[E + e];
    int pos = offs[dst] + atomicAdd(&cursor[dst], 1);
    pairs[pos] = make_int2(ei[e], __float_as_int(ew[e]));
}

// ---------------- W prep: transpose + split fp32 -> bf16 hi/lo planes ----------
// Wt[n][k], n in [0,256): n<128 = Wl col n, n>=128 = Wr col n-128. Fragment-
// order so gemm A-frag = 8 contiguous bf16 per lane (global_load_dwordx4).

template<int K>
__global__ void wprep_kernel(const float* __restrict__ Wl, const float* __restrict__ Wr,
                             short* __restrict__ Wth, short* __restrict__ Wtl) {
    const int k = blockIdx.x;
    const int t = threadIdx.x;
    const float v = (t < 128) ? Wl[k * 128 + t] : Wr[k * 128 + (t - 128)];
    const short h = bf16_rne(v);
    Wth[(size_t)t * K + k] = h;
    Wtl[(size_t)t * K + k] = bf16_rne(v - bf16f(h));
}

// ---------------- split-bf16 MFMA GEMM: [outL|outR] = X[R x K] @ [Wl|Wr] --------
// 64 rows x 256 cols per block (4 waves); wave = 16 X-rows x 16 col-tiles.
// Operands SWAPPED vs R8: A = W-frag (m-dim = W col), B = X-frag (n-dim = X row)
// so D has col=lane&15 = X row, row=quad*4+reg = W col -> each lane stores
// float4 (4 consecutive cols of one out row): proven-coalesced write shape.
// 3 MFMA per tile (hi*hi + lo*hi + hi*lo) ~ fp32 accuracy (validated R8).
// FULL unroll everywhere acc is indexed -- R8's `#pragma unroll 4` left acc[]
// dynamically indexed -> scratch spill -> 650 MB of HBM RMW. Never again.

template<int K>
__global__ __launch_bounds__(256) void gemm_mfma_kernel(
    const float* __restrict__ X,
    const short* __restrict__ Wth, const short* __restrict__ Wtl,
    float* __restrict__ outL, float* __restrict__ outR) {
    const int tid = threadIdx.x;
    const int wv = tid >> 6;
    const int lane = tid & 63;
    const int q = lane >> 4;
    const int mr = lane & 15;
    const int xrow = blockIdx.x * 64 + wv * 16 + mr;

    f32x4 acc[16];
    #pragma unroll
    for (int t = 0; t < 16; ++t) acc[t] = (f32x4){0.f, 0.f, 0.f, 0.f};

    const float* xp  = X + (size_t)xrow * K + q * 8;
    const short* wh0 = Wth + (size_t)mr * K + q * 8;   // + t*16*K per col-tile
    const short* wl0 = Wtl + (size_t)mr * K + q * 8;

    #pragma unroll
    for (int k0 = 0; k0 < K; k0 += 32) {
        const float4 a0 = *(const float4*)(xp + k0);
        const float4 a1 = *(const float4*)(xp + k0 + 4);
        const float av[8] = {a0.x, a0.y, a0.z, a0.w, a1.x, a1.y, a1.z, a1.w};
        bf16x8 xh, xl;
        #pragma unroll
        for (int j = 0; j < 8; ++j) {
            const short h = bf16_rne(av[j]);
            xh[j] = h;
            xl[j] = bf16_rne(av[j] - bf16f(h));
        }
        #pragma unroll
        for (int t = 0; t < 16; ++t) {
            const bf16x8 wh = *(const bf16x8*)(wh0 + (size_t)t * 16 * K + k0);
            const bf16x8 wl = *(const bf16x8*)(wl0 + (size_t)t * 16 * K + k0);
            acc[t] = __builtin_amdgcn_mfma_f32_16x16x32_bf16(wh, xh, acc[t], 0, 0, 0);
            acc[t] = __builtin_amdgcn_mfma_f32_16x16x32_bf16(wl, xh, acc[t], 0, 0, 0);
            acc[t] = __builtin_amdgcn_mfma_f32_16x16x32_bf16(wh, xl, acc[t], 0, 0, 0);
        }
    }

    // lane owns out[xrow][tile*16 + q*4 .. +3] for each of 16 tiles (8 L, 8 R)
    const size_t ob = (size_t)xrow * 128 + q * 4;
    #pragma unroll
    for (int t = 0; t < 8; ++t) {
        *(float4*)(outL + ob + t * 16) =
            make_float4(acc[t][0], acc[t][1], acc[t][2], acc[t][3]);
        *(float4*)(outR + ob + t * 16) =
            make_float4(acc[t + 8][0], acc[t + 8][1], acc[t + 8][2], acc[t + 8][3]);
    }
}

// ---------------- fused edge softmax-aggregate (R7-proven, unchanged) ----------

__global__ __launch_bounds__(256) void edge_kernel(
    const float* __restrict__ xl, const float* __restrict__ xr,
    const int* __restrict__ offs, const int2* __restrict__ pairs,
    const float* __restrict__ self_w,
    const float* __restrict__ att, const float* __restrict__ We,
    const float* __restrict__ bias, float* __restrict__ out,
    int N, int M) {
    const int wave = __builtin_amdgcn_readfirstlane(threadIdx.x >> 6);
    const int b = blockIdx.x;
    const int hb = (b >= 10000) ? (b - 10000) : b;
    const int m = ((b >= 10000) ? 8 : 0) + (hb & 7);
    const int n = (hb >> 3) * 4 + wave;
    if (n >= N) return;
    const int lane = threadIdx.x & 63;

    const int c2 = lane << 1;
    float2 att2 = *(const float2*)(att + c2);
    att2.x *= LOG2E_C; att2.y *= LOG2E_C;     // exp2 domain
    const float2 we2 = *(const float2*)(We + c2);

    const float* xlm = xl + (size_t)m * N * 128;
    const float* xrm = xr + (size_t)m * N * 128;
    const int rowb = n << 7;
    const float2 xi2 = *(const float2*)(xrm + rowb + c2);

    float base, lsum;
    float2 acc;
    {   // self-loop first; its logit becomes the softmax base (t = 1)
        const float sw = self_w[n];
        const float2 xj = *(const float2*)(xlm + rowb + c2);
        float sx = fmaf(sw, we2.x, xi2.x) + xj.x;
        float sy = fmaf(sw, we2.y, xi2.y) + xj.y;
        sx = fmaf(NEG_SLOPE_C - 1.0f, fminf(sx, 0.f), sx);
        sy = fmaf(NEG_SLOPE_C - 1.0f, fminf(sy, 0.f), sy);
        base = half_reduce(fmaf(sy, att2.y, sx * att2.x));
        lsum = 1.f; acc = xj;
    }

    const int beg = offs[n], end = offs[n + 1];
    int e = beg;
    for (; e + 2 <= end; e += 2) {
        const int2 prA = pairs[e];
        const int2 prB = pairs[e + 1];
        const float wA = __int_as_float(prA.y);
        const float wB = __int_as_float(prB.y);
        const float2 xjA = *(const float2*)(xlm + (prA.x << 7) + c2);
        const float2 xjB = *(const float2*)(xlm + (prB.x << 7) + c2);
        float sxA = fmaf(wA, we2.x, xi2.x) + xjA.x;
        float syA = fmaf(wA, we2.y, xi2.y) + xjA.y;
        float sxB = fmaf(wB, we2.x, xi2.x) + xjB.x;
        float syB = fmaf(wB, we2.y, xi2.y) + xjB.y;
        sxA = fmaf(NEG_SLOPE_C - 1.0f, fminf(sxA, 0.f), sxA);
        syA = fmaf(NEG_SLOPE_C - 1.0f, fminf(syA, 0.f), syA);
        sxB = fmaf(NEG_SLOPE_C - 1.0f, fminf(sxB, 0.f), sxB);
        syB = fmaf(NEG_SLOPE_C - 1.0f, fminf(syB, 0.f), syB);
        float qA = half_reduce(fmaf(syA, att2.y, sxA * att2.x));
        float qB = half_reduce(fmaf(syB, att2.y, sxB * att2.x));
        const float tA = EXP2F(qA - base);
        const float tB = EXP2F(qB - base);
        lsum += tA + tB;
        acc.x = fmaf(tA, xjA.x, acc.x);
        acc.y = fmaf(tA, xjA.y, acc.y);
        acc.x = fmaf(tB, xjB.x, acc.x);
        acc.y = fmaf(tB, xjB.y, acc.y);
    }
    if (e < end) {
        const int2 pr = pairs[e];
        const float w = __int_as_float(pr.y);
        const float2 xj = *(const float2*)(xlm + (pr.x << 7) + c2);
        float sx = fmaf(w, we2.x, xi2.x) + xj.x;
        float sy = fmaf(w, we2.y, xi2.y) + xj.y;
        sx = fmaf(NEG_SLOPE_C - 1.0f, fminf(sx, 0.f), sx);
        sy = fmaf(NEG_SLOPE_C - 1.0f, fminf(sy, 0.f), sy);
        float q = half_reduce(fmaf(sy, att2.y, sx * att2.x));
        const float t = EXP2F(q - base);
        lsum += t;
        acc.x = fmaf(t, xj.x, acc.x);
        acc.y = fmaf(t, xj.y, acc.y);
    }

    const float inv = 1.f / (lsum + EPS_C);
    const float2 b2v = *(const float2*)(bias + c2);
    float ox = fmaf(acc.x, inv, b2v.x);
    float oy = fmaf(acc.y, inv, b2v.y);
    ox = ox > 0.f ? ox : (__expf(ox) - 1.f);   // ELU
    oy = oy > 0.f ? oy : (__expf(oy) - 1.f);
    *(float2*)(out + (size_t)m * N * 128 + rowb + c2) = make_float2(ox, oy);
}

// ---------------- launch ----------------

extern "C" void kernel_launch(void* const* d_in, const int* in_sizes, int n_in,
                              void* d_out, int out_size, void* d_ws, size_t ws_size,
                              hipStream_t stream) {
    const float* x    = (const float*)d_in[0];
    const int*   ei   = (const int*)d_in[1];
    const float* ew   = (const float*)d_in[2];
    const float* Wl1  = (const float*)d_in[3];
    const float* Wr1  = (const float*)d_in[4];
    const float* att1 = (const float*)d_in[5];
    const float* We1  = (const float*)d_in[6];
    const float* b1   = (const float*)d_in[7];
    const float* Wl2  = (const float*)d_in[8];
    const float* Wr2  = (const float*)d_in[9];
    const float* att2 = (const float*)d_in[10];
    const float* We2  = (const float*)d_in[11];
    const float* b2   = (const float*)d_in[12];

    const int E = in_sizes[1] / 2;
    const int N = 5000;                 // fixed by setup_inputs
    const int R = out_size / 128;       // M*N rows
    const int M = R / N;                // B*T = 16

    char* ws = (char*)d_ws;
    size_t off = 0;
    auto alloc = [&](size_t bytes) {
        char* p = ws + off;
        off = (off + bytes + 255) & ~(size_t)255;
        return p;
    };
    int*   cnt    = (int*)  alloc((size_t)N * 4);
    float* wsum   = (float*)alloc((size_t)N * 4);
    float* selfw  = (float*)alloc((size_t)N * 4);
    int*   offs   = (int*)  alloc((size_t)(N + 1) * 4);
    int*   cursor = (int*)  alloc((size_t)N * 4);
    int2*  pairs  = (int2*) alloc((size_t)E * 8);
    short* wt1h   = (short*)alloc((size_t)256 * 64 * 2);
    short* wt1l   = (short*)alloc((size_t)256 * 64 * 2);
    short* wt2h   = (short*)alloc((size_t)256 * 128 * 2);
    short* wt2l   = (short*)alloc((size_t)256 * 128 * 2);
    float* bufA   = (float*)alloc((size_t)R * 128 * 4);
    float* bufB   = (float*)alloc((size_t)R * 128 * 4);
    float* bufC   = (float*)alloc((size_t)R * 128 * 4);

    hipMemsetAsync(cnt,    0, (size_t)N * 4, stream);
    hipMemsetAsync(wsum,   0, (size_t)N * 4, stream);
    hipMemsetAsync(cursor, 0, (size_t)N * 4, stream);

    int eb = (E + 255) / 256;
    degree_kernel<<<eb, 256, 0, stream>>>(ei, ew, E, cnt, wsum);
    scan_kernel<<<1, 1024, 0, stream>>>(cnt, wsum, N, E, offs, selfw);
    scatter_kernel<<<eb, 256, 0, stream>>>(ei, ew, E, offs, cursor, pairs);
    wprep_kernel<64><<<64, 256, 0, stream>>>(Wl1, Wr1, wt1h, wt1l);
    wprep_kernel<128><<<128, 256, 0, stream>>>(Wl2, Wr2, wt2h, wt2l);

    const int gb = R / 64;
    const int tb = 2 * ((N + 3) / 4) * 8;   // 20000 blocks: XCD-swizzled task map

    // layer 1: K=64
    gemm_mfma_kernel<64><<<gb, 256, 0, stream>>>(x, wt1h, wt1l, bufA, bufB);
    edge_kernel<<<tb, 256, 0, stream>>>(bufA, bufB, offs, pairs, selfw,
                                        att1, We1, b1, bufC, N, M);
    // layer 2: K=128
    gemm_mfma_kernel<128><<<gb, 256, 0, stream>>>(bufC, wt2h, wt2l, bufA, bufB);
    edge_kernel<<<tb, 256, 0, stream>>>(bufA, bufB, offs, pairs, selfw,
                                        att2, We2, b2, (float*)d_out, N, M);
}

// Round 10
// 307.236 us; speedup vs baseline: 1.7031x; 1.3107x over previous
//
#include <hip/hip_runtime.h>
#include <cstdint>
#include <cstddef>

static constexpr float NEG_SLOPE_C = 0.2f;
static constexpr float EPS_C = 1e-16f;
static constexpr float LOG2E_C = 1.4426950408889634f;

#if defined(__has_builtin)
#if __has_builtin(__builtin_amdgcn_exp2f)
#define EXP2F(x) __builtin_amdgcn_exp2f(x)
#else
#define EXP2F(x) exp2f(x)
#endif
#else
#define EXP2F(x) exp2f(x)
#endif

typedef __attribute__((ext_vector_type(8))) short bf16x8;
typedef __attribute__((ext_vector_type(4))) float f32x4;

__device__ __forceinline__ short bf16_rne(float x) {
    unsigned u = __float_as_uint(x);
    u = (u + 0x7FFF + ((u >> 16) & 1)) >> 16;
    return (short)u;
}
__device__ __forceinline__ float bf16f(short s) {
    return __uint_as_float(((unsigned)(unsigned short)s) << 16);
}

// DPP-based partial-sum add: v += dpp_perm(v).
template<int CTRL>
__device__ __forceinline__ float dpp_add_f(float v) {
    int x = __builtin_amdgcn_update_dpp(0, __float_as_int(v), CTRL, 0xf, 0xf, true);
    return v + __int_as_float(x);
}

// 32-lane-half reduction of q (both heads at once), result in every lane.
__device__ __forceinline__ float half_reduce(float q) {
    q = dpp_add_f<0xB1>(q);      // xor1 (quad_perm [1,0,3,2])
    q = dpp_add_f<0x4E>(q);      // xor2 (quad_perm [2,3,0,1])
    q = dpp_add_f<0x141>(q);     // half-mirror: pairs quads
    q = dpp_add_f<0x140>(q);     // mirror: pairs octs
    q += __int_as_float(__builtin_amdgcn_ds_swizzle(__float_as_int(q), 0x401F)); // xor16
    return q;
}

// ---------------- CSR construction ----------------

__global__ void degree_kernel(const int* __restrict__ ei, const float* __restrict__ ew,
                              int E, int* __restrict__ cnt, float* __restrict__ wsum) {
    int e = blockIdx.x * blockDim.x + threadIdx.x;
    if (e >= E) return;
    int dst = ei[E + e];
    atomicAdd(&cnt[dst], 1);
    atomicAdd(&wsum[dst], ew[e]);
}

__global__ void scan_kernel(const int* __restrict__ cnt, const float* __restrict__ wsum,
                            int N, int E, int* __restrict__ offs, float* __restrict__ self_w) {
    __shared__ int bufA[1024];
    __shared__ int bufB[1024];
    int t = threadIdx.x;
    int chunk = (N + 1023) / 1024;
    int lo = t * chunk;
    int hi = lo + chunk; if (hi > N) hi = N; if (lo > N) lo = N;
    int s = 0;
    for (int n = lo; n < hi; ++n) s += cnt[n];
    bufA[t] = s;
    __syncthreads();
    int* srcb = bufA; int* dstb = bufB;
    for (int d = 1; d < 1024; d <<= 1) {
        int v = srcb[t];
        if (t >= d) v += srcb[t - d];
        dstb[t] = v;
        __syncthreads();
        int* tmp = srcb; srcb = dstb; dstb = tmp;
    }
    int run = (t == 0) ? 0 : srcb[t - 1];
    for (int n = lo; n < hi; ++n) { offs[n] = run; run += cnt[n]; }
    if (t == 0) offs[N] = E;
    for (int n = t; n < N; n += 1024) {
        int c = cnt[n];
        self_w[n] = (c > 0) ? (wsum[n] / (float)c) : 0.0f;
    }
}

__global__ void scatter_kernel(const int* __restrict__ ei, const float* __restrict__ ew, int E,
                               const int* __restrict__ offs, int* __restrict__ cursor,
                               int2* __restrict__ pairs) {
    int e = blockIdx.x * blockDim.x + threadIdx.x;
    if (e >= E) return;
    int dst = ei[E + e];
    int pos = offs[dst] + atomicAdd(&cursor[dst], 1);
    pairs[pos] = make_int2(ei[e], __float_as_int(ew[e]));
}

// ---------------- W prep: fp32 -> split-bf16 hi/lo in MFMA FRAGMENT ORDER -----
// Wf unit u = 16 B (one lane-frag). Layout: u = s*2048 + (t*2+p)*64 + lane,
// s = k-slice (32 k), t = col-tile (16 cols; t<8 -> Wl, t>=8 -> Wr), p = hi/lo,
// lane = q*16+mr: frag = plane p of W[k = s*32+q*8+j][col = t*16+mr], j=0..7.
// A k-slice is a contiguous 32 KB block -> gemm stages it with coalesced copies.

template<int K>
__global__ void wprep_kernel(const float* __restrict__ Wl, const float* __restrict__ Wr,
                             uint4* __restrict__ Wf) {
    const int gid = blockIdx.x * 256 + threadIdx.x;   // (K/32)*16*64 threads
    const int lane = gid & 63;
    const int t = (gid >> 6) & 15;
    const int s = gid >> 10;
    const int mr = lane & 15, q = lane >> 4;
    const int col = t * 16 + mr;
    const float* src = (col < 128) ? (Wl + col) : (Wr + col - 128);
    union { short sh[8]; uint4 u; } hv, lv;
    #pragma unroll
    for (int j = 0; j < 8; ++j) {
        const float v = src[(size_t)(s * 32 + q * 8 + j) * 128];
        const short h = bf16_rne(v);
        hv.sh[j] = h;
        lv.sh[j] = bf16_rne(v - bf16f(h));
    }
    const size_t base = (size_t)s * 2048 + (size_t)(t * 2) * 64 + lane;
    Wf[base] = hv.u;          // hi plane
    Wf[base + 64] = lv.u;     // lo plane
}

// ---------------- split-bf16 MFMA GEMM: [outL|outR] = X[R x K] @ [Wl|Wr] --------
// 64 rows x 256 cols per block (4 waves); wave = 16 X-rows x 16 col-tiles.
// Per k-slice (32 k): cooperatively stage the 32 KB fragment-ordered W slice
// into LDS (coalesced uint4, 8/thread), then frag reads are conflict-free
// ds_read_b128 shared by all 4 waves. Fixes R9's latency collapse (scattered
// per-wave L2 round-trips, L1 thrash, MfmaUtil 6%).
// A = W-frag, B = X-frag, D col=lane&15 = X row, row=q*4+reg = W col (R9-proven).
// FULL unroll wherever acc[] is indexed (R8 spill lesson).

template<int K>
__global__ __launch_bounds__(256) void gemm_mfma_kernel(
    const float* __restrict__ X, const uint4* __restrict__ Wf,
    float* __restrict__ outL, float* __restrict__ outR) {
    __shared__ uint4 wbuf[2048];          // 32 KB: one k-slice, fragment order
    const int tid = threadIdx.x;
    const int wv = tid >> 6;
    const int lane = tid & 63;
    const int q = lane >> 4;
    const int mr = lane & 15;
    const int xrow = blockIdx.x * 64 + wv * 16 + mr;

    f32x4 acc[16];
    #pragma unroll
    for (int t = 0; t < 16; ++t) acc[t] = (f32x4){0.f, 0.f, 0.f, 0.f};

    const float* xp = X + (size_t)xrow * K + q * 8;

    for (int s = 0; s < K / 32; ++s) {
        // issue X load early (HBM stream) so latency overlaps staging+barrier
        const float4 a0 = *(const float4*)(xp + s * 32);
        const float4 a1 = *(const float4*)(xp + s * 32 + 4);

        __syncthreads();                   // previous slice fully consumed
        const uint4* gsrc = Wf + (size_t)s * 2048 + wv * 512 + lane;
        #pragma unroll
        for (int i = 0; i < 8; ++i)
            wbuf[wv * 512 + i * 64 + lane] = gsrc[i * 64];
        __syncthreads();                   // slice visible

        const float av[8] = {a0.x, a0.y, a0.z, a0.w, a1.x, a1.y, a1.z, a1.w};
        bf16x8 xh, xl;
        #pragma unroll
        for (int j = 0; j < 8; ++j) {
            const short h = bf16_rne(av[j]);
            xh[j] = h;
            xl[j] = bf16_rne(av[j] - bf16f(h));
        }
        #pragma unroll
        for (int t = 0; t < 16; ++t) {
            const bf16x8 wh = *(const bf16x8*)&wbuf[(t * 2) * 64 + lane];
            const bf16x8 wl = *(const bf16x8*)&wbuf[(t * 2 + 1) * 64 + lane];
            acc[t] = __builtin_amdgcn_mfma_f32_16x16x32_bf16(wh, xh, acc[t], 0, 0, 0);
            acc[t] = __builtin_amdgcn_mfma_f32_16x16x32_bf16(wl, xh, acc[t], 0, 0, 0);
            acc[t] = __builtin_amdgcn_mfma_f32_16x16x32_bf16(wh, xl, acc[t], 0, 0, 0);
        }
    }

    // lane owns out[xrow][tile*16 + q*4 .. +3] for each of 16 tiles (8 L, 8 R)
    const size_t ob = (size_t)xrow * 128 + q * 4;
    #pragma unroll
    for (int t = 0; t < 8; ++t) {
        *(float4*)(outL + ob + t * 16) =
            make_float4(acc[t][0], acc[t][1], acc[t][2], acc[t][3]);
        *(float4*)(outR + ob + t * 16) =
            make_float4(acc[t + 8][0], acc[t + 8][1], acc[t + 8][2], acc[t + 8][3]);
    }
}

// ---------------- fused edge softmax-aggregate (R7-proven, unchanged) ----------

__global__ __launch_bounds__(256) void edge_kernel(
    const float* __restrict__ xl, const float* __restrict__ xr,
    const int* __restrict__ offs, const int2* __restrict__ pairs,
    const float* __restrict__ self_w,
    const float* __restrict__ att, const float* __restrict__ We,
    const float* __restrict__ bias, float* __restrict__ out,
    int N, int M) {
    const int wave = __builtin_amdgcn_readfirstlane(threadIdx.x >> 6);
    const int b = blockIdx.x;
    const int hb = (b >= 10000) ? (b - 10000) : b;
    const int m = ((b >= 10000) ? 8 : 0) + (hb & 7);
    const int n = (hb >> 3) * 4 + wave;
    if (n >= N) return;
    const int lane = threadIdx.x & 63;

    const int c2 = lane << 1;
    float2 att2 = *(const float2*)(att + c2);
    att2.x *= LOG2E_C; att2.y *= LOG2E_C;     // exp2 domain
    const float2 we2 = *(const float2*)(We + c2);

    const float* xlm = xl + (size_t)m * N * 128;
    const float* xrm = xr + (size_t)m * N * 128;
    const int rowb = n << 7;
    const float2 xi2 = *(const float2*)(xrm + rowb + c2);

    float base, lsum;
    float2 acc;
    {   // self-loop first; its logit becomes the softmax base (t = 1)
        const float sw = self_w[n];
        const float2 xj = *(const float2*)(xlm + rowb + c2);
        float sx = fmaf(sw, we2.x, xi2.x) + xj.x;
        float sy = fmaf(sw, we2.y, xi2.y) + xj.y;
        sx = fmaf(NEG_SLOPE_C - 1.0f, fminf(sx, 0.f), sx);
        sy = fmaf(NEG_SLOPE_C - 1.0f, fminf(sy, 0.f), sy);
        base = half_reduce(fmaf(sy, att2.y, sx * att2.x));
        lsum = 1.f; acc = xj;
    }

    const int beg = offs[n], end = offs[n + 1];
    int e = beg;
    for (; e + 2 <= end; e += 2) {
        const int2 prA = pairs[e];
        const int2 prB = pairs[e + 1];
        const float wA = __int_as_float(prA.y);
        const float wB = __int_as_float(prB.y);
        const float2 xjA = *(const float2*)(xlm + (prA.x << 7) + c2);
        const float2 xjB = *(const float2*)(xlm + (prB.x << 7) + c2);
        float sxA = fmaf(wA, we2.x, xi2.x) + xjA.x;
        float syA = fmaf(wA, we2.y, xi2.y) + xjA.y;
        float sxB = fmaf(wB, we2.x, xi2.x) + xjB.x;
        float syB = fmaf(wB, we2.y, xi2.y) + xjB.y;
        sxA = fmaf(NEG_SLOPE_C - 1.0f, fminf(sxA, 0.f), sxA);
        syA = fmaf(NEG_SLOPE_C - 1.0f, fminf(syA, 0.f), syA);
        sxB = fmaf(NEG_SLOPE_C - 1.0f, fminf(sxB, 0.f), sxB);
        syB = fmaf(NEG_SLOPE_C - 1.0f, fminf(syB, 0.f), syB);
        float qA = half_reduce(fmaf(syA, att2.y, sxA * att2.x));
        float qB = half_reduce(fmaf(syB, att2.y, sxB * att2.x));
        const float tA = EXP2F(qA - base);
        const float tB = EXP2F(qB - base);
        lsum += tA + tB;
        acc.x = fmaf(tA, xjA.x, acc.x);
        acc.y = fmaf(tA, xjA.y, acc.y);
        acc.x = fmaf(tB, xjB.x, acc.x);
        acc.y = fmaf(tB, xjB.y, acc.y);
    }
    if (e < end) {
        const int2 pr = pairs[e];
        const float w = __int_as_float(pr.y);
        const float2 xj = *(const float2*)(xlm + (pr.x << 7) + c2);
        float sx = fmaf(w, we2.x, xi2.x) + xj.x;
        float sy = fmaf(w, we2.y, xi2.y) + xj.y;
        sx = fmaf(NEG_SLOPE_C - 1.0f, fminf(sx, 0.f), sx);
        sy = fmaf(NEG_SLOPE_C - 1.0f, fminf(sy, 0.f), sy);
        float q = half_reduce(fmaf(sy, att2.y, sx * att2.x));
        const float t = EXP2F(q - base);
        lsum += t;
        acc.x = fmaf(t, xj.x, acc.x);
        acc.y = fmaf(t, xj.y, acc.y);
    }

    const float inv = 1.f / (lsum + EPS_C);
    const float2 b2v = *(const float2*)(bias + c2);
    float ox = fmaf(acc.x, inv, b2v.x);
    float oy = fmaf(acc.y, inv, b2v.y);
    ox = ox > 0.f ? ox : (__expf(ox) - 1.f);   // ELU
    oy = oy > 0.f ? oy : (__expf(oy) - 1.f);
    *(float2*)(out + (size_t)m * N * 128 + rowb + c2) = make_float2(ox, oy);
}

// ---------------- launch ----------------

extern "C" void kernel_launch(void* const* d_in, const int* in_sizes, int n_in,
                              void* d_out, int out_size, void* d_ws, size_t ws_size,
                              hipStream_t stream) {
    const float* x    = (const float*)d_in[0];
    const int*   ei   = (const int*)d_in[1];
    const float* ew   = (const float*)d_in[2];
    const float* Wl1  = (const float*)d_in[3];
    const float* Wr1  = (const float*)d_in[4];
    const float* att1 = (const float*)d_in[5];
    const float* We1  = (const float*)d_in[6];
    const float* b1   = (const float*)d_in[7];
    const float* Wl2  = (const float*)d_in[8];
    const float* Wr2  = (const float*)d_in[9];
    const float* att2 = (const float*)d_in[10];
    const float* We2  = (const float*)d_in[11];
    const float* b2   = (const float*)d_in[12];

    const int E = in_sizes[1] / 2;
    const int N = 5000;                 // fixed by setup_inputs
    const int R = out_size / 128;       // M*N rows
    const int M = R / N;                // B*T = 16

    char* ws = (char*)d_ws;
    size_t off = 0;
    auto alloc = [&](size_t bytes) {
        char* p = ws + off;
        off = (off + bytes + 255) & ~(size_t)255;
        return p;
    };
    int*   cnt    = (int*)  alloc((size_t)N * 4);
    float* wsum   = (float*)alloc((size_t)N * 4);
    float* selfw  = (float*)alloc((size_t)N * 4);
    int*   offs   = (int*)  alloc((size_t)(N + 1) * 4);
    int*   cursor = (int*)  alloc((size_t)N * 4);
    int2*  pairs  = (int2*) alloc((size_t)E * 8);
    uint4* wf1    = (uint4*)alloc((size_t)2 * 2048 * 16);   // K=64: 64 KB
    uint4* wf2    = (uint4*)alloc((size_t)4 * 2048 * 16);   // K=128: 128 KB
    float* bufA   = (float*)alloc((size_t)R * 128 * 4);
    float* bufB   = (float*)alloc((size_t)R * 128 * 4);
    float* bufC   = (float*)alloc((size_t)R * 128 * 4);

    hipMemsetAsync(cnt,    0, (size_t)N * 4, stream);
    hipMemsetAsync(wsum,   0, (size_t)N * 4, stream);
    hipMemsetAsync(cursor, 0, (size_t)N * 4, stream);

    int eb = (E + 255) / 256;
    degree_kernel<<<eb, 256, 0, stream>>>(ei, ew, E, cnt, wsum);
    scan_kernel<<<1, 1024, 0, stream>>>(cnt, wsum, N, E, offs, selfw);
    scatter_kernel<<<eb, 256, 0, stream>>>(ei, ew, E, offs, cursor, pairs);
    wprep_kernel<64><<<8, 256, 0, stream>>>(Wl1, Wr1, wf1);
    wprep_kernel<128><<<16, 256, 0, stream>>>(Wl2, Wr2, wf2);

    const int gb = R / 64;
    const int tb = 2 * ((N + 3) / 4) * 8;   // 20000 blocks: XCD-swizzled task map

    // layer 1: K=64
    gemm_mfma_kernel<64><<<gb, 256, 0, stream>>>(x, wf1, bufA, bufB);
    edge_kernel<<<tb, 256, 0, stream>>>(bufA, bufB, offs, pairs, selfw,
                                        att1, We1, b1, bufC, N, M);
    // layer 2: K=128
    gemm_mfma_kernel<128><<<gb, 256, 0, stream>>>(bufC, wf2, bufA, bufB);
    edge_kernel<<<tb, 256, 0, stream>>>(bufA, bufB, offs, pairs, selfw,
                                        att2, We2, b2, (float*)d_out, N, M);
}

// Round 11
// 295.698 us; speedup vs baseline: 1.7695x; 1.0390x over previous
//
#include <hip/hip_runtime.h>
#include <cstdint>
#include <cstddef>

static constexpr float NEG_SLOPE_C = 0.2f;
static constexpr float EPS_C = 1e-16f;
static constexpr float LOG2E_C = 1.4426950408889634f;

#if defined(__has_builtin)
#if __has_builtin(__builtin_amdgcn_exp2f)
#define EXP2F(x) __builtin_amdgcn_exp2f(x)
#else
#define EXP2F(x) exp2f(x)
#endif
#else
#define EXP2F(x) exp2f(x)
#endif

typedef __attribute__((ext_vector_type(8))) short bf16x8;
typedef __attribute__((ext_vector_type(4))) float f32x4;

__device__ __forceinline__ short bf16_rne(float x) {
    unsigned u = __float_as_uint(x);
    u = (u + 0x7FFF + ((u >> 16) & 1)) >> 16;
    return (short)u;
}
__device__ __forceinline__ float bf16f(short s) {
    return __uint_as_float(((unsigned)(unsigned short)s) << 16);
}

// DPP-based partial-sum add: v += dpp_perm(v).
template<int CTRL>
__device__ __forceinline__ float dpp_add_f(float v) {
    int x = __builtin_amdgcn_update_dpp(0, __float_as_int(v), CTRL, 0xf, 0xf, true);
    return v + __int_as_float(x);
}

// Reduce within each 16-lane row (4 DPP steps, no DS). All 16 lanes of a
// row end with the row sum.
__device__ __forceinline__ float reduce16(float q) {
    q = dpp_add_f<0xB1>(q);      // xor1 (quad_perm [1,0,3,2])
    q = dpp_add_f<0x4E>(q);      // xor2 (quad_perm [2,3,0,1])
    q = dpp_add_f<0x141>(q);     // xor4 (row_half_mirror)
    q = dpp_add_f<0x140>(q);     // xor8 (row_mirror)
    return q;
}

// ---------------- CSR construction ----------------

__global__ void degree_kernel(const int* __restrict__ ei, const float* __restrict__ ew,
                              int E, int* __restrict__ cnt, float* __restrict__ wsum) {
    int e = blockIdx.x * blockDim.x + threadIdx.x;
    if (e >= E) return;
    int dst = ei[E + e];
    atomicAdd(&cnt[dst], 1);
    atomicAdd(&wsum[dst], ew[e]);
}

__global__ void scan_kernel(const int* __restrict__ cnt, const float* __restrict__ wsum,
                            int N, int E, int* __restrict__ offs, float* __restrict__ self_w) {
    __shared__ int bufA[1024];
    __shared__ int bufB[1024];
    int t = threadIdx.x;
    int chunk = (N + 1023) / 1024;
    int lo = t * chunk;
    int hi = lo + chunk; if (hi > N) hi = N; if (lo > N) lo = N;
    int s = 0;
    for (int n = lo; n < hi; ++n) s += cnt[n];
    bufA[t] = s;
    __syncthreads();
    int* srcb = bufA; int* dstb = bufB;
    for (int d = 1; d < 1024; d <<= 1) {
        int v = srcb[t];
        if (t >= d) v += srcb[t - d];
        dstb[t] = v;
        __syncthreads();
        int* tmp = srcb; srcb = dstb; dstb = tmp;
    }
    int run = (t == 0) ? 0 : srcb[t - 1];
    for (int n = lo; n < hi; ++n) { offs[n] = run; run += cnt[n]; }
    if (t == 0) offs[N] = E;
    for (int n = t; n < N; n += 1024) {
        int c = cnt[n];
        self_w[n] = (c > 0) ? (wsum[n] / (float)c) : 0.0f;
    }
}

__global__ void scatter_kernel(const int* __restrict__ ei, const float* __restrict__ ew, int E,
                               const int* __restrict__ offs, int* __restrict__ cursor,
                               int2* __restrict__ pairs) {
    int e = blockIdx.x * blockDim.x + threadIdx.x;
    if (e >= E) return;
    int dst = ei[E + e];
    int pos = offs[dst] + atomicAdd(&cursor[dst], 1);
    pairs[pos] = make_int2(ei[e], __float_as_int(ew[e]));
}

// ---------------- W prep: fp32 -> split-bf16 hi/lo in MFMA FRAGMENT ORDER -----

template<int K>
__global__ void wprep_kernel(const float* __restrict__ Wl, const float* __restrict__ Wr,
                             uint4* __restrict__ Wf) {
    const int gid = blockIdx.x * 256 + threadIdx.x;   // (K/32)*16*64 threads
    const int lane = gid & 63;
    const int t = (gid >> 6) & 15;
    const int s = gid >> 10;
    const int mr = lane & 15, q = lane >> 4;
    const int col = t * 16 + mr;
    const float* src = (col < 128) ? (Wl + col) : (Wr + col - 128);
    union { short sh[8]; uint4 u; } hv, lv;
    #pragma unroll
    for (int j = 0; j < 8; ++j) {
        const float v = src[(size_t)(s * 32 + q * 8 + j) * 128];
        const short h = bf16_rne(v);
        hv.sh[j] = h;
        lv.sh[j] = bf16_rne(v - bf16f(h));
    }
    const size_t base = (size_t)s * 2048 + (size_t)(t * 2) * 64 + lane;
    Wf[base] = hv.u;          // hi plane
    Wf[base + 64] = lv.u;     // lo plane
}

// ---------------- split-bf16 MFMA GEMM (R10-proven, unchanged) ----------------

template<int K>
__global__ __launch_bounds__(256) void gemm_mfma_kernel(
    const float* __restrict__ X, const uint4* __restrict__ Wf,
    float* __restrict__ outL, float* __restrict__ outR) {
    __shared__ uint4 wbuf[2048];          // 32 KB: one k-slice, fragment order
    const int tid = threadIdx.x;
    const int wv = tid >> 6;
    const int lane = tid & 63;
    const int q = lane >> 4;
    const int mr = lane & 15;
    const int xrow = blockIdx.x * 64 + wv * 16 + mr;

    f32x4 acc[16];
    #pragma unroll
    for (int t = 0; t < 16; ++t) acc[t] = (f32x4){0.f, 0.f, 0.f, 0.f};

    const float* xp = X + (size_t)xrow * K + q * 8;

    for (int s = 0; s < K / 32; ++s) {
        const float4 a0 = *(const float4*)(xp + s * 32);
        const float4 a1 = *(const float4*)(xp + s * 32 + 4);

        __syncthreads();                   // previous slice fully consumed
        const uint4* gsrc = Wf + (size_t)s * 2048 + wv * 512 + lane;
        #pragma unroll
        for (int i = 0; i < 8; ++i)
            wbuf[wv * 512 + i * 64 + lane] = gsrc[i * 64];
        __syncthreads();                   // slice visible

        const float av[8] = {a0.x, a0.y, a0.z, a0.w, a1.x, a1.y, a1.z, a1.w};
        bf16x8 xh, xl;
        #pragma unroll
        for (int j = 0; j < 8; ++j) {
            const short h = bf16_rne(av[j]);
            xh[j] = h;
            xl[j] = bf16_rne(av[j] - bf16f(h));
        }
        #pragma unroll
        for (int t = 0; t < 16; ++t) {
            const bf16x8 wh = *(const bf16x8*)&wbuf[(t * 2) * 64 + lane];
            const bf16x8 wl = *(const bf16x8*)&wbuf[(t * 2 + 1) * 64 + lane];
            acc[t] = __builtin_amdgcn_mfma_f32_16x16x32_bf16(wh, xh, acc[t], 0, 0, 0);
            acc[t] = __builtin_amdgcn_mfma_f32_16x16x32_bf16(wl, xh, acc[t], 0, 0, 0);
            acc[t] = __builtin_amdgcn_mfma_f32_16x16x32_bf16(wh, xl, acc[t], 0, 0, 0);
        }
    }

    const size_t ob = (size_t)xrow * 128 + q * 4;
    #pragma unroll
    for (int t = 0; t < 8; ++t) {
        *(float4*)(outL + ob + t * 16) =
            make_float4(acc[t][0], acc[t][1], acc[t][2], acc[t][3]);
        *(float4*)(outR + ob + t * 16) =
            make_float4(acc[t + 8][0], acc[t + 8][1], acc[t + 8][2], acc[t + 8][3]);
    }
}

// ---------------- fused edge softmax-aggregate: TWO edges per wave ------------
// Lane l: half p = l>>5 (edge of the pair), j = l&31, channels 4j..4j+3.
// Head 0 = lanes 0-15 of each half, head 1 = lanes 16-31. Per-head dot-reduce
// = 4 DPP steps within 16 lanes -- NO DS op in the loop; cross-half combine
// happens once per node at the end (shfl_xor 32). Self-loop contributes 0.5x
// from each half (exact). Odd tail: half 1 duplicates the edge, t zeroed.
// XCD-affinity swizzle (R7-proven) unchanged.

__global__ __launch_bounds__(256) void edge_kernel(
    const float* __restrict__ xl, const float* __restrict__ xr,
    const int* __restrict__ offs, const int2* __restrict__ pairs,
    const float* __restrict__ self_w,
    const float* __restrict__ att, const float* __restrict__ We,
    const float* __restrict__ bias, float* __restrict__ out,
    int N, int M) {
    const int wave = __builtin_amdgcn_readfirstlane(threadIdx.x >> 6);
    const int b = blockIdx.x;
    const int hb = (b >= 10000) ? (b - 10000) : b;
    const int m = ((b >= 10000) ? 8 : 0) + (hb & 7);
    const int n = (hb >> 3) * 4 + wave;
    if (n >= N) return;
    const int lane = threadIdx.x & 63;
    const int j = lane & 31;
    const bool hi = lane >= 32;

    const float4* xlm4 = (const float4*)(xl + (size_t)m * N * 128);
    const float4* xrm4 = (const float4*)(xr + (size_t)m * N * 128);

    float4 att4 = ((const float4*)att)[j];
    att4.x *= LOG2E_C; att4.y *= LOG2E_C; att4.z *= LOG2E_C; att4.w *= LOG2E_C;
    const float4 we4 = ((const float4*)We)[j];
    const float4 xi4 = xrm4[n * 32 + j];

    float base, lsum;
    float4 acc;
    {   // self-loop: both halves compute it; each contributes 0.5x (exact)
        const float sw = self_w[n];
        const float4 xj = xlm4[n * 32 + j];
        float s0 = fmaf(sw, we4.x, xi4.x) + xj.x;
        float s1 = fmaf(sw, we4.y, xi4.y) + xj.y;
        float s2 = fmaf(sw, we4.z, xi4.z) + xj.z;
        float s3 = fmaf(sw, we4.w, xi4.w) + xj.w;
        s0 = fmaf(NEG_SLOPE_C - 1.0f, fminf(s0, 0.f), s0);
        s1 = fmaf(NEG_SLOPE_C - 1.0f, fminf(s1, 0.f), s1);
        s2 = fmaf(NEG_SLOPE_C - 1.0f, fminf(s2, 0.f), s2);
        s3 = fmaf(NEG_SLOPE_C - 1.0f, fminf(s3, 0.f), s3);
        float q = s0 * att4.x;
        q = fmaf(s1, att4.y, q);
        q = fmaf(s2, att4.z, q);
        q = fmaf(s3, att4.w, q);
        base = reduce16(q);               // per-row = per-head self logit
        lsum = 0.5f;
        acc = make_float4(xj.x * 0.5f, xj.y * 0.5f, xj.z * 0.5f, xj.w * 0.5f);
    }

    const int beg = offs[n], end = offs[n + 1];
    int e = beg;
    #pragma unroll 2
    for (; e + 2 <= end; e += 2) {
        const int2 prA = pairs[e];
        const int2 prB = pairs[e + 1];
        const int src = hi ? prB.x : prA.x;
        const float w = __int_as_float(hi ? prB.y : prA.y);
        const float4 xj = xlm4[src * 32 + j];
        float s0 = fmaf(w, we4.x, xi4.x) + xj.x;
        float s1 = fmaf(w, we4.y, xi4.y) + xj.y;
        float s2 = fmaf(w, we4.z, xi4.z) + xj.z;
        float s3 = fmaf(w, we4.w, xi4.w) + xj.w;
        s0 = fmaf(NEG_SLOPE_C - 1.0f, fminf(s0, 0.f), s0);
        s1 = fmaf(NEG_SLOPE_C - 1.0f, fminf(s1, 0.f), s1);
        s2 = fmaf(NEG_SLOPE_C - 1.0f, fminf(s2, 0.f), s2);
        s3 = fmaf(NEG_SLOPE_C - 1.0f, fminf(s3, 0.f), s3);
        float q = s0 * att4.x;
        q = fmaf(s1, att4.y, q);
        q = fmaf(s2, att4.z, q);
        q = fmaf(s3, att4.w, q);
        q = reduce16(q);
        const float t = EXP2F(q - base);
        lsum += t;
        acc.x = fmaf(t, xj.x, acc.x);
        acc.y = fmaf(t, xj.y, acc.y);
        acc.z = fmaf(t, xj.z, acc.z);
        acc.w = fmaf(t, xj.w, acc.w);
    }
    if (e < end) {   // odd tail: both halves same edge; half 1 zeroed
        const int2 pr = pairs[e];
        const int src = pr.x;
        const float w = __int_as_float(pr.y);
        const float4 xj = xlm4[src * 32 + j];
        float s0 = fmaf(w, we4.x, xi4.x) + xj.x;
        float s1 = fmaf(w, we4.y, xi4.y) + xj.y;
        float s2 = fmaf(w, we4.z, xi4.z) + xj.z;
        float s3 = fmaf(w, we4.w, xi4.w) + xj.w;
        s0 = fmaf(NEG_SLOPE_C - 1.0f, fminf(s0, 0.f), s0);
        s1 = fmaf(NEG_SLOPE_C - 1.0f, fminf(s1, 0.f), s1);
        s2 = fmaf(NEG_SLOPE_C - 1.0f, fminf(s2, 0.f), s2);
        s3 = fmaf(NEG_SLOPE_C - 1.0f, fminf(s3, 0.f), s3);
        float q = s0 * att4.x;
        q = fmaf(s1, att4.y, q);
        q = fmaf(s2, att4.z, q);
        q = fmaf(s3, att4.w, q);
        q = reduce16(q);
        float t = EXP2F(q - base);
        t = hi ? 0.f : t;
        lsum += t;
        acc.x = fmaf(t, xj.x, acc.x);
        acc.y = fmaf(t, xj.y, acc.y);
        acc.z = fmaf(t, xj.z, acc.z);
        acc.w = fmaf(t, xj.w, acc.w);
    }

    // cross-half combine (once per node)
    lsum += __shfl_xor(lsum, 32, 64);
    acc.x += __shfl_xor(acc.x, 32, 64);
    acc.y += __shfl_xor(acc.y, 32, 64);
    acc.z += __shfl_xor(acc.z, 32, 64);
    acc.w += __shfl_xor(acc.w, 32, 64);

    const float inv = 1.f / (lsum + EPS_C);
    const float4 b4 = ((const float4*)bias)[j];
    float o0 = fmaf(acc.x, inv, b4.x);
    float o1 = fmaf(acc.y, inv, b4.y);
    float o2 = fmaf(acc.z, inv, b4.z);
    float o3 = fmaf(acc.w, inv, b4.w);
    o0 = o0 > 0.f ? o0 : (__expf(o0) - 1.f);
    o1 = o1 > 0.f ? o1 : (__expf(o1) - 1.f);
    o2 = o2 > 0.f ? o2 : (__expf(o2) - 1.f);
    o3 = o3 > 0.f ? o3 : (__expf(o3) - 1.f);
    if (!hi) {
        ((float4*)(out + (size_t)m * N * 128))[n * 32 + j] =
            make_float4(o0, o1, o2, o3);
    }
}

// ---------------- launch ----------------

extern "C" void kernel_launch(void* const* d_in, const int* in_sizes, int n_in,
                              void* d_out, int out_size, void* d_ws, size_t ws_size,
                              hipStream_t stream) {
    const float* x    = (const float*)d_in[0];
    const int*   ei   = (const int*)d_in[1];
    const float* ew   = (const float*)d_in[2];
    const float* Wl1  = (const float*)d_in[3];
    const float* Wr1  = (const float*)d_in[4];
    const float* att1 = (const float*)d_in[5];
    const float* We1  = (const float*)d_in[6];
    const float* b1   = (const float*)d_in[7];
    const float* Wl2  = (const float*)d_in[8];
    const float* Wr2  = (const float*)d_in[9];
    const float* att2 = (const float*)d_in[10];
    const float* We2  = (const float*)d_in[11];
    const float* b2   = (const float*)d_in[12];

    const int E = in_sizes[1] / 2;
    const int N = 5000;                 // fixed by setup_inputs
    const int R = out_size / 128;       // M*N rows
    const int M = R / N;                // B*T = 16

    char* ws = (char*)d_ws;
    size_t off = 0;
    auto alloc = [&](size_t bytes) {
        char* p = ws + off;
        off = (off + bytes + 255) & ~(size_t)255;
        return p;
    };
    int*   cnt    = (int*)  alloc((size_t)N * 4);
    float* wsum   = (float*)alloc((size_t)N * 4);
    float* selfw  = (float*)alloc((size_t)N * 4);
    int*   offs   = (int*)  alloc((size_t)(N + 1) * 4);
    int*   cursor = (int*)  alloc((size_t)N * 4);
    int2*  pairs  = (int2*) alloc((size_t)E * 8);
    uint4* wf1    = (uint4*)alloc((size_t)2 * 2048 * 16);   // K=64: 64 KB
    uint4* wf2    = (uint4*)alloc((size_t)4 * 2048 * 16);   // K=128: 128 KB
    float* bufA   = (float*)alloc((size_t)R * 128 * 4);
    float* bufB   = (float*)alloc((size_t)R * 128 * 4);
    float* bufC   = (float*)alloc((size_t)R * 128 * 4);

    hipMemsetAsync(cnt,    0, (size_t)N * 4, stream);
    hipMemsetAsync(wsum,   0, (size_t)N * 4, stream);
    hipMemsetAsync(cursor, 0, (size_t)N * 4, stream);

    int eb = (E + 255) / 256;
    degree_kernel<<<eb, 256, 0, stream>>>(ei, ew, E, cnt, wsum);
    scan_kernel<<<1, 1024, 0, stream>>>(cnt, wsum, N, E, offs, selfw);
    scatter_kernel<<<eb, 256, 0, stream>>>(ei, ew, E, offs, cursor, pairs);
    wprep_kernel<64><<<8, 256, 0, stream>>>(Wl1, Wr1, wf1);
    wprep_kernel<128><<<16, 256, 0, stream>>>(Wl2, Wr2, wf2);

    const int gb = R / 64;
    const int tb = 2 * ((N + 3) / 4) * 8;   // 20000 blocks: XCD-swizzled task map

    // layer 1: K=64
    gemm_mfma_kernel<64><<<gb, 256, 0, stream>>>(x, wf1, bufA, bufB);
    edge_kernel<<<tb, 256, 0, stream>>>(bufA, bufB, offs, pairs, selfw,
                                        att1, We1, b1, bufC, N, M);
    // layer 2: K=128
    gemm_mfma_kernel<128><<<gb, 256, 0, stream>>>(bufC, wf2, bufA, bufB);
    edge_kernel<<<tb, 256, 0, stream>>>(bufA, bufB, offs, pairs, selfw,
                                        att2, We2, b2, (float*)d_out, N, M);
}